// Round 2
// baseline (70.592 us; speedup 1.0000x reference)
//
#include <hip/hip_runtime.h>

// out[b,t] = -sum_{i=0}^{15} lpc[b, t/160, i] * x[b, t-i],  x[<0] = 0
// B=1024, T=2400, N=16, F=160. All float32.
//
// One thread -> 4 consecutive outputs (one float4 store). F=160 divisible
// by 4, so all 4 outputs share one lpc row. x window x[t-16 .. t+3] is 5
// aligned float4 loads (t multiple of 4 -> 16B aligned).
//
// Rationale vs OPT=8/16: the harness poison-fill (256 MiB) evicts L3 every
// iteration, so input reads are HBM-cold. The kernel is latency-bound, not
// BW-bound (ideal traffic ~21 MB = 3.3 us). OPT=4 quadruples thread count
// vs OPT=16 (2400 blocks, up to 32 waves/CU with launch_bounds(256,8)) to
// maximize memory-level parallelism during the cold-fetch ramp.
// 1D grid: exactly B * (T/4) = 614400 threads -> 2400 blocks, no tail.

__global__ __launch_bounds__(256, 8) void lpc_pred_kernel(
    const float* __restrict__ xt,   // [B, T]
    const float* __restrict__ lpc,  // [B, T/F, N]
    float* __restrict__ out)        // [B, T]
{
    constexpr int T = 2400;
    constexpr int N = 16;
    constexpr int F = 160;
    constexpr int FRAMES = T / F;   // 15
    constexpr int OPT = 4;          // outputs per thread
    constexpr int GPR = T / OPT;    // 600 groups per row

    const int tid = blockIdx.x * 256 + threadIdx.x;   // exactly B*GPR threads
    const int b = tid / GPR;
    const int j = tid - b * GPR;
    const int t = j * OPT;

    const float* __restrict__ xrow = xt + (size_t)b * T;
    const float* __restrict__ crow = lpc + ((size_t)b * FRAMES + (t / F)) * N;

    // 16 coefficients: 4 aligned float4 loads (crow is 64B-aligned).
    float cc[16];
    {
        const float4* cp = (const float4*)crow;
        #pragma unroll
        for (int k = 0; k < 4; ++k) {
            float4 v = cp[k];
            cc[4 * k + 0] = v.x; cc[4 * k + 1] = v.y;
            cc[4 * k + 2] = v.z; cc[4 * k + 3] = v.w;
        }
    }

    // xv[m] = x[t - 16 + m], m in [0, 20)
    float xv[20];
    if (t >= 16) {
        const float4* xp = (const float4*)(xrow + t - 16);
        #pragma unroll
        for (int k = 0; k < 5; ++k) {
            float4 v = xp[k];
            xv[4 * k + 0] = v.x; xv[4 * k + 1] = v.y;
            xv[4 * k + 2] = v.z; xv[4 * k + 3] = v.w;
        }
    } else {
        // only j in {0..3} per row hits this (zero-pad region)
        #pragma unroll
        for (int m = 0; m < 20; ++m) {
            int g = t - 16 + m;
            xv[m] = (g >= 0) ? xrow[g] : 0.0f;
        }
    }

    // acc[d] = -sum_i cc[i] * x[t + d - i]; x[t+d-i] = xv[16 + d - i]
    float acc[4];
    #pragma unroll
    for (int d = 0; d < OPT; ++d) {
        float s = 0.0f;
        #pragma unroll
        for (int i = 0; i < N; ++i) {
            s += cc[i] * xv[16 + d - i];
        }
        acc[d] = -s;
    }

    float* orow = out + (size_t)b * T + t;
    *(float4*)orow = make_float4(acc[0], acc[1], acc[2], acc[3]);
}

extern "C" void kernel_launch(void* const* d_in, const int* in_sizes, int n_in,
                              void* d_out, int out_size, void* d_ws, size_t ws_size,
                              hipStream_t stream) {
    const float* xt  = (const float*)d_in[0];
    const float* lpc = (const float*)d_in[1];
    float* out = (float*)d_out;

    constexpr int B = 1024;
    constexpr int T = 2400;
    constexpr int OPT = 4;
    constexpr int THREADS = B * (T / OPT);  // 614400

    dim3 grid(THREADS / 256);  // 2400 blocks, exact
    dim3 block(256);
    lpc_pred_kernel<<<grid, block, 0, stream>>>(xt, lpc, out);
}

// Round 4
// 66.291 us; speedup vs baseline: 1.0649x; 1.0649x over previous
//
#include <hip/hip_runtime.h>

// out[b,t] = -sum_{i=0}^{15} lpc[b, t/160, i] * x[b, t-i],  x[<0] = 0
// B=1024, T=2400, N=16, F=160. All float32.
//
// One thread -> 8 consecutive outputs (two nontemporal 16B stores).
// F=160 divisible by 8, so all 8 outputs share one lpc row. x window
// x[t-16 .. t+7] is 6 aligned float4 loads. 1D grid: exactly B * (T/8)
// threads, no tail.
//
// Session finding (rounds 0-2): dur_us is dominated by the harness's
// 256 MiB poison fill (~41-45 us at ~80% HBM peak, visible as the only
// top-5 dispatches) + fixed reset overhead; kernel itself is ~5-10 us
// (roofline: ~21 MB cold HBM = 3.3 us). OPT in {4,8,16} all land within
// fill noise; OPT=8 was best-measured. Output stores are nontemporal
// (native ext_vector_type, since __builtin_nontemporal_store rejects
// HIP_vector_type float4*): out is never re-read, skip cache allocation.

typedef float vfloat4 __attribute__((ext_vector_type(4)));

__global__ __launch_bounds__(256) void lpc_pred_kernel(
    const float* __restrict__ xt,   // [B, T]
    const float* __restrict__ lpc,  // [B, T/F, N]
    float* __restrict__ out)        // [B, T]
{
    constexpr int T = 2400;
    constexpr int N = 16;
    constexpr int F = 160;
    constexpr int FRAMES = T / F;   // 15
    constexpr int OPT = 8;          // outputs per thread
    constexpr int GPR = T / OPT;    // 300 groups per row

    const int tid = blockIdx.x * 256 + threadIdx.x;   // exactly B*GPR threads
    const int b = tid / GPR;
    const int j = tid - b * GPR;
    const int t = j * OPT;

    const float* __restrict__ xrow = xt + (size_t)b * T;
    const float* __restrict__ crow = lpc + ((size_t)b * FRAMES + (t / F)) * N;

    // 16 coefficients: 4 aligned float4 loads (crow is 64B-aligned).
    float cc[16];
    {
        const float4* cp = (const float4*)crow;
        #pragma unroll
        for (int k = 0; k < 4; ++k) {
            float4 v = cp[k];
            cc[4 * k + 0] = v.x; cc[4 * k + 1] = v.y;
            cc[4 * k + 2] = v.z; cc[4 * k + 3] = v.w;
        }
    }

    // xv[m] = x[t - 16 + m], m in [0, 24)
    float xv[24];
    if (t >= 16) {
        const float4* xp = (const float4*)(xrow + t - 16);
        #pragma unroll
        for (int k = 0; k < 6; ++k) {
            float4 v = xp[k];
            xv[4 * k + 0] = v.x; xv[4 * k + 1] = v.y;
            xv[4 * k + 2] = v.z; xv[4 * k + 3] = v.w;
        }
    } else {
        // only j in {0,1} per row hits this (zero-pad region)
        #pragma unroll
        for (int m = 0; m < 24; ++m) {
            int g = t - 16 + m;
            xv[m] = (g >= 0) ? xrow[g] : 0.0f;
        }
    }

    // acc[d] = -sum_i cc[i] * x[t + d - i]; x[t+d-i] = xv[16 + d - i]
    float acc[8];
    #pragma unroll
    for (int d = 0; d < OPT; ++d) {
        float s = 0.0f;
        #pragma unroll
        for (int i = 0; i < N; ++i) {
            s += cc[i] * xv[16 + d - i];
        }
        acc[d] = -s;
    }

    float* orow = out + (size_t)b * T + t;
    vfloat4 lo = { acc[0], acc[1], acc[2], acc[3] };
    vfloat4 hi = { acc[4], acc[5], acc[6], acc[7] };
    __builtin_nontemporal_store(lo, (vfloat4*)(orow + 0));
    __builtin_nontemporal_store(hi, (vfloat4*)(orow + 4));
}

extern "C" void kernel_launch(void* const* d_in, const int* in_sizes, int n_in,
                              void* d_out, int out_size, void* d_ws, size_t ws_size,
                              hipStream_t stream) {
    const float* xt  = (const float*)d_in[0];
    const float* lpc = (const float*)d_in[1];
    float* out = (float*)d_out;

    constexpr int B = 1024;
    constexpr int T = 2400;
    constexpr int OPT = 8;
    constexpr int THREADS = B * (T / OPT);  // 307200

    dim3 grid(THREADS / 256);  // 1200 blocks, exact
    dim3 block(256);
    lpc_pred_kernel<<<grid, block, 0, stream>>>(xt, lpc, out);
}